// Round 11
// baseline (1040.184 us; speedup 1.0000x reference)
//
#include <hip/hip_runtime.h>
#include <hip/hip_bf16.h>

typedef __attribute__((ext_vector_type(4))) float f32x4;
typedef __attribute__((ext_vector_type(8))) short short8;

#define DEVI __device__ __forceinline__

DEVI unsigned short f2bf(float x) {
  union { float f; unsigned u; } v; v.f = x;
  unsigned r = v.u + 0x7fffu + ((v.u >> 16) & 1u);
  return (unsigned short)(r >> 16);
}
DEVI float bf2f(unsigned short h) {
  union { unsigned u; float f; } v; v.u = ((unsigned)h) << 16;
  return v.f;
}
DEVI short8 pack8(f32x4 lo, f32x4 hi) {
  short8 r;
  r[0] = (short)f2bf(lo[0]); r[1] = (short)f2bf(lo[1]);
  r[2] = (short)f2bf(lo[2]); r[3] = (short)f2bf(lo[3]);
  r[4] = (short)f2bf(hi[0]); r[5] = (short)f2bf(hi[1]);
  r[6] = (short)f2bf(hi[2]); r[7] = (short)f2bf(hi[3]);
  return r;
}

DEVI void gld16(const void* g, void* l) {
  __builtin_amdgcn_global_load_lds(
      (const __attribute__((address_space(1))) void*)g,
      (__attribute__((address_space(3))) void*)l, 16, 0, 0);
}

// ---------- prep ----------
// whh0/whh1 -> bf16 in MFMA-fragment order, WAVE-OUTERMOST so each wave's 64
// fragments are contiguous (1 KB stride walk):
//   element e: slot=e>>3, r=e&7; lane=slot&63, ni=(slot>>6)&3, kt=(slot>>8)&15,
//   wd=slot>>12; col=wd*64+ni*16+(lane&15); kr=kt*32+(lane>>4)*8+r.
__global__ __launch_bounds__(256) void prep_cvt(
    const float* __restrict__ whh0, const float* __restrict__ whh1,
    const float* __restrict__ wih1, const float* __restrict__ wih0,
    short* __restrict__ o_whh0fr, short* __restrict__ o_whh1fr,
    short* __restrict__ o_wih1, short* __restrict__ o_wih0) {
  int i = blockIdx.x * 256 + threadIdx.x;
  if (i < 524288) {
    const float* src = (i < 262144) ? whh0 : whh1;
    short* dst = (i < 262144) ? o_whh0fr : o_whh1fr;
    int e = i & 262143;
    int slot = e >> 3, r = e & 7;
    int lane = slot & 63, ni = (slot >> 6) & 3, kt = (slot >> 8) & 15, wd = slot >> 12;
    int col = wd * 64 + ni * 16 + (lane & 15);
    int kr = kt * 32 + (lane >> 4) * 8 + r;
    dst[e] = (short)f2bf(src[col * 512 + kr]);
    return;
  }
  if (i < 786432) { int j = i - 524288; o_wih1[j] = (short)f2bf(wih1[j]); return; }
  if (i < 917504) { int j = i - 786432; o_wih0[j] = (short)f2bf(wih0[j]); return; }
}

// ---------- GEMM: pre = A @ W^T + bias_a + bias_b  (bf16 out) ----------
// XCD-aware block swizzle: the 4 bN-tiles of one bM land on the same XCD.
template<int KDIM, bool GATHER>
__global__ __launch_bounds__(256) void gemm_pre(
    const float* __restrict__ embed, const int* __restrict__ xtok,
    const short* __restrict__ Abf, const short* __restrict__ Bbf,
    const float* __restrict__ bias_a, const float* __restrict__ bias_b,
    short* __restrict__ out) {
  __shared__ short smem[16384];          // As[128][64] @0, Bs[128][64] @8192 (shorts)
  short* As = smem;
  short* Bs = smem + 8192;

  const int tid = threadIdx.x;
  const int p = (int)blockIdx.x;
  const int bN = (p >> 3) & 3;
  const int bM = ((p >> 5) << 3) | (p & 7);
  const int m0 = bM * 128, n0 = bN * 128;

  f32x4 acc[4][4];
#pragma unroll
  for (int i = 0; i < 4; ++i)
#pragma unroll
    for (int j = 0; j < 4; ++j) acc[i][j] = (f32x4){0.f, 0.f, 0.f, 0.f};

  const int lane = tid & 63, wid = tid >> 6;
  const int wm = wid >> 1, wn = wid & 1;
  const int l15 = lane & 15, lk = lane >> 4;

  const int srow = tid >> 1;
  const int skh = (tid & 1) * 32;
  const int sxor = (srow & 7) << 4;
  const int sbyte0 = srow * 128 + skh * 2;

  const float* aG = nullptr;
  const short* aB = nullptr;
  if (GATHER) {
    int r = m0 + srow;
    int t = r >> 11, n = r & 2047;
    int tok = xtok[(n << 5) + t];
    aG = embed + (size_t)tok * 256;
  } else {
    aB = Abf + (size_t)(m0 + srow) * KDIM;
  }
  const short* bRow = Bbf + (size_t)(n0 + srow) * KDIM;

  for (int kb = 0; kb < KDIM; kb += 64) {
    __syncthreads();
#pragma unroll
    for (int c = 0; c < 4; ++c) {
      short8 pa;
      if (GATHER) {
        const float* src = aG + kb + skh + c * 8;
        f32x4 lo = *(const f32x4*)(src);
        f32x4 hi = *(const f32x4*)(src + 4);
        pa = pack8(lo, hi);
      } else {
        pa = *(const short8*)(aB + kb + skh + c * 8);
      }
      *(short8*)((char*)As + ((sbyte0 + c * 16) ^ sxor)) = pa;
      short8 pb = *(const short8*)(bRow + kb + skh + c * 8);
      *(short8*)((char*)Bs + ((sbyte0 + c * 16) ^ sxor)) = pb;
    }
    __syncthreads();
#pragma unroll
    for (int kt = 0; kt < 2; ++kt) {
      short8 av[4], bv[4];
#pragma unroll
      for (int mi = 0; mi < 4; ++mi) {
        int row = wm * 64 + mi * 16 + l15;
        int off = (row * 128 + kt * 64 + lk * 16) ^ ((row & 7) << 4);
        av[mi] = *(const short8*)((const char*)As + off);
      }
#pragma unroll
      for (int ni = 0; ni < 4; ++ni) {
        int col = wn * 64 + ni * 16 + l15;
        int off = (col * 128 + kt * 64 + lk * 16) ^ ((col & 7) << 4);
        bv[ni] = *(const short8*)((const char*)Bs + off);
      }
#pragma unroll
      for (int mi = 0; mi < 4; ++mi)
#pragma unroll
        for (int ni = 0; ni < 4; ++ni)
          acc[mi][ni] = __builtin_amdgcn_mfma_f32_16x16x32_bf16(av[mi], bv[ni], acc[mi][ni], 0, 0, 0);
    }
  }
  __syncthreads();
  float bsum[4];
#pragma unroll
  for (int ni = 0; ni < 4; ++ni) {
    int cg = n0 + wn * 64 + ni * 16 + l15;
    bsum[ni] = bias_a[cg] + bias_b[cg];
  }
  short* Cs = smem;
#pragma unroll
  for (int mi = 0; mi < 4; ++mi)
#pragma unroll
    for (int ni = 0; ni < 4; ++ni)
#pragma unroll
      for (int r = 0; r < 4; ++r) {
        int row = wm * 64 + mi * 16 + lk * 4 + r;
        int col = wn * 64 + ni * 16 + l15;
        Cs[row * 128 + col] = (short)f2bf(acc[mi][ni][r] + bsum[ni]);
      }
  __syncthreads();
  {
    int row = tid >> 1, colh = (tid & 1) * 64;
    size_t gbase = (size_t)(m0 + row) * 512 + n0 + colh;
#pragma unroll
    for (int c = 0; c < 8; ++c)
      *(short8*)(out + gbase + c * 8) = *(const short8*)&Cs[row * 128 + colh + c * 8];
  }
}

// ---------- recurrence: h_t = relu(pre_t + h_{t-1} @ W_hh^T) ----------
// 128 blocks x 512 threads. Pure circular L2->VGPR W streamer:
//   16 named short8 buffers (64 VGPR) in 4 banks; KT_STEP(k) consumes bank
//   (k&3) for kt=k and reloads it with kt=k+4's fragments (contiguous walk,
//   rp += 2KB). KT_STEP(12..15) prefetch next step's kt0..3 (W is identical
//   every step -> perfectly circular, no boundary bubble). No manual vmcnt:
//   compiler inserts exact per-buffer waits. Peak VGPR demand ~105.
// LDS only 32 KB: hl (h tile, XOR-swizzled) + plds (pre tile).
template<bool WRITE_OUTS>
__global__ __launch_bounds__(512) void recur(
    const short* __restrict__ pre,   // [32][2048][512] bf16
    const short* __restrict__ wfr,   // W_hh frag order, wave-outermost (see prep)
    short* __restrict__ outs,        // [32][2048][512] bf16 (WRITE_OUTS)
    float* __restrict__ hlast) {     // [2048][512] f32 (!WRITE_OUTS)
  __shared__ __align__(16) char lds[32768];
  char* hl   = lds;            // 16 KB: h tile 16x512 bf16, XOR-swizzled
  char* plds = lds + 16384;    // 16 KB: pre tile 16x512 bf16, linear
  const int tid = threadIdx.x;
  const int lane = tid & 63, wid = tid >> 6;
  const int l15 = lane & 15, lk = lane >> 4;
  const int n0 = (int)blockIdx.x * 16;

  // per-lane fragment base: this wave's 64 KB contiguous region
  const short* wsl = wfr + wid * 32768 + lane * 8;

  // prologue: f banks hold kt0..kt3
  short8 f0  = *(const short8*)(wsl + 0);
  short8 f1  = *(const short8*)(wsl + 512);
  short8 f2  = *(const short8*)(wsl + 1024);
  short8 f3  = *(const short8*)(wsl + 1536);
  short8 f4  = *(const short8*)(wsl + 2048);
  short8 f5  = *(const short8*)(wsl + 2560);
  short8 f6  = *(const short8*)(wsl + 3072);
  short8 f7  = *(const short8*)(wsl + 3584);
  short8 f8  = *(const short8*)(wsl + 4096);
  short8 f9  = *(const short8*)(wsl + 4608);
  short8 f10 = *(const short8*)(wsl + 5120);
  short8 f11 = *(const short8*)(wsl + 5632);
  short8 f12 = *(const short8*)(wsl + 6144);
  short8 f13 = *(const short8*)(wsl + 6656);
  short8 f14 = *(const short8*)(wsl + 7168);
  short8 f15 = *(const short8*)(wsl + 7680);

  {  // zero h(-1)
    short8 z = {0, 0, 0, 0, 0, 0, 0, 0};
    *(short8*)(hl + tid * 32) = z;
    *(short8*)(hl + tid * 32 + 16) = z;
  }
  __syncthreads();

  const int axor = (l15 & 7) << 4;
  const int lk16 = lk * 16;
  const char* abase = hl + l15 * 1024;
  const int crow = tid >> 5, cseg = tid & 31;
  const int cxor = (crow & 7) << 4;

  const short* rp = wsl + 8192;  // reload cursor: fragment 16 (= kt4, ni0)

#define KT_STEP(KT, FA, FB, FC, FD)                                           \
  {                                                                           \
    short8 a = *(const short8*)(abase + (((KT) * 64 + lk16) ^ axor));         \
    acc[0] = __builtin_amdgcn_mfma_f32_16x16x32_bf16(a, FA, acc[0], 0, 0, 0); \
    acc[1] = __builtin_amdgcn_mfma_f32_16x16x32_bf16(a, FB, acc[1], 0, 0, 0); \
    acc[2] = __builtin_amdgcn_mfma_f32_16x16x32_bf16(a, FC, acc[2], 0, 0, 0); \
    acc[3] = __builtin_amdgcn_mfma_f32_16x16x32_bf16(a, FD, acc[3], 0, 0, 0); \
    FA = *(const short8*)(rp);                                                \
    FB = *(const short8*)(rp + 512);                                          \
    FC = *(const short8*)(rp + 1024);                                         \
    FD = *(const short8*)(rp + 1536);                                         \
    rp += 2048;                                                               \
  }

#pragma unroll 1
  for (int t = 0; t < 32; ++t) {
    // stage pre rows 2*wid, 2*wid+1 (consumed after B1)
    {
      const short* psrc = pre + ((size_t)t * 2048 + n0) * 512;
      gld16(psrc + wid * 1024 + lane * 8, plds + wid * 2048);
      gld16(psrc + wid * 1024 + 512 + lane * 8, plds + wid * 2048 + 1024);
    }

    f32x4 acc[4];
#pragma unroll
    for (int ni = 0; ni < 4; ++ni) acc[ni] = (f32x4){0.f, 0.f, 0.f, 0.f};

    KT_STEP(0,  f0,  f1,  f2,  f3)     // reload <- kt4
    KT_STEP(1,  f4,  f5,  f6,  f7)     // reload <- kt5
    KT_STEP(2,  f8,  f9,  f10, f11)    // reload <- kt6
    KT_STEP(3,  f12, f13, f14, f15)    // reload <- kt7
    KT_STEP(4,  f0,  f1,  f2,  f3)     // reload <- kt8
    KT_STEP(5,  f4,  f5,  f6,  f7)     // reload <- kt9
    KT_STEP(6,  f8,  f9,  f10, f11)    // reload <- kt10
    KT_STEP(7,  f12, f13, f14, f15)    // reload <- kt11
    KT_STEP(8,  f0,  f1,  f2,  f3)     // reload <- kt12
    KT_STEP(9,  f4,  f5,  f6,  f7)     // reload <- kt13
    KT_STEP(10, f8,  f9,  f10, f11)    // reload <- kt14
    KT_STEP(11, f12, f13, f14, f15)    // reload <- kt15
    rp = wsl;                          // wrap: next reloads = next step's kt0..3
    KT_STEP(12, f0,  f1,  f2,  f3)     // reload <- kt0'
    KT_STEP(13, f4,  f5,  f6,  f7)     // reload <- kt1'
    KT_STEP(14, f8,  f9,  f10, f11)    // reload <- kt2'
    KT_STEP(15, f12, f13, f14, f15)    // reload <- kt3'  (rp back to wsl+8192)

    // stream h(t-1) to outs (reads hl; must precede B1/epilogue)
    if (WRITE_OUTS && t > 0) {
      short8 v0 = *(const short8*)(hl + crow * 1024 + ((cseg * 32) ^ cxor));
      short8 v1 = *(const short8*)(hl + crow * 1024 + ((cseg * 32 + 16) ^ cxor));
      short* dst = outs + ((size_t)(t - 1) * 2048 + n0 + crow) * 512 + cseg * 16;
      *(short8*)dst = v0;
      *(short8*)(dst + 8) = v1;
    }

    __syncthreads();  // B1: drains vmcnt(0) -> plds staged; h(t-1) reads done

    // epilogue: h(t) = relu(acc + pre) in place (XOR-swizzled)
#pragma unroll
    for (int r = 0; r < 4; ++r) {
      int row = lk * 4 + r;
      int rxor = (row & 7) << 4;
#pragma unroll
      for (int ni = 0; ni < 4; ++ni) {
        int col = wid * 64 + ni * 16 + l15;
        float pvf = bf2f(*(const unsigned short*)(plds + row * 1024 + col * 2));
        float v = fmaxf(acc[ni][r] + pvf, 0.f);
        *(short*)(hl + row * 1024 + ((col * 2) ^ rxor)) = (short)f2bf(v);
        if (!WRITE_OUTS && t == 31) hlast[(size_t)(n0 + row) * 512 + col] = v;
      }
    }
    __syncthreads();  // B2: h(t) visible to all
  }
#undef KT_STEP

  if (WRITE_OUTS) {
    short8 v0 = *(const short8*)(hl + crow * 1024 + ((cseg * 32) ^ cxor));
    short8 v1 = *(const short8*)(hl + crow * 1024 + ((cseg * 32 + 16) ^ cxor));
    short* dst = outs + ((size_t)31 * 2048 + n0 + crow) * 512 + cseg * 16;
    *(short8*)dst = v0;
    *(short8*)(dst + 8) = v1;
  }
}

// ---------- head: s[b,n] = h_n.(wl-wg) + (sum_n h).wg + b_pred ----------
__global__ __launch_bounds__(512) void predict(
    const float* __restrict__ h1, const float* __restrict__ Wp,
    const float* __restrict__ bp, float* __restrict__ out) {
  const int b = blockIdx.x, tid = threadIdx.x;
  const int lane = tid & 63, wid = tid >> 6;
  __shared__ float red[8];
  __shared__ float sgd_s;
  const float* hb = h1 + (size_t)b * 256 * 512;
  float s = 0.f;
  for (int n = 0; n < 256; ++n) s += hb[(size_t)n * 512 + tid];
  float p = s * Wp[512 + tid];
#pragma unroll
  for (int o = 32; o; o >>= 1) p += __shfl_xor(p, o);
  if (lane == 0) red[wid] = p;
  __syncthreads();
  if (tid == 0) {
    float q = 0.f;
#pragma unroll
    for (int i = 0; i < 8; ++i) q += red[i];
    sgd_s = q;
  }
  __syncthreads();
  const float sgd = sgd_s + bp[0];
  float wd[8];
  const int k0 = lane * 8;
#pragma unroll
  for (int j = 0; j < 8; ++j) wd[j] = Wp[k0 + j] - Wp[512 + k0 + j];
  for (int c = 0; c < 32; ++c) {
    int n = wid * 32 + c;
    const float* hr = hb + (size_t)n * 512 + k0;
    float d = 0.f;
#pragma unroll
    for (int j = 0; j < 8; ++j) d += hr[j] * wd[j];
#pragma unroll
    for (int o = 1; o < 64; o <<= 1) d += __shfl_xor(d, o);
    if (lane == 0) out[b * 256 + n] = d + sgd;
  }
}

extern "C" void kernel_launch(void* const* d_in, const int* in_sizes, int n_in,
                              void* d_out, int out_size, void* d_ws, size_t ws_size,
                              hipStream_t stream) {
  const int* x = (const int*)d_in[0];
  const float* embed = (const float*)d_in[1];
  const float* Wih0 = (const float*)d_in[2];
  const float* Whh0 = (const float*)d_in[3];
  const float* bih0 = (const float*)d_in[4];
  const float* bhh0 = (const float*)d_in[5];
  const float* Wih1 = (const float*)d_in[6];
  const float* Whh1 = (const float*)d_in[7];
  const float* bih1 = (const float*)d_in[8];
  const float* bhh1 = (const float*)d_in[9];
  const float* Wpred = (const float*)d_in[10];
  const float* bpred = (const float*)d_in[11];
  float* out = (float*)d_out;

  char* ws = (char*)d_ws;
  short* whh0_fr = (short*)ws;                          // 512 KB (frag order)
  short* whh1_fr = (short*)(ws + 524288);               // 512 KB (frag order)
  short* wih0_bf = (short*)(ws + 1048576);              // 256 KB
  short* wih1_bf = (short*)(ws + 1310720);              // 512 KB
  short* pre     = (short*)(ws + 2097152);              // 64 MB (pre0, then pre1)
  short* outs0   = (short*)(ws + 2097152 + 67108864);   // 64 MB
  float* h1      = (float*)(ws + 2097152 + 2ll * 67108864);  // 4 MB

  prep_cvt<<<3584, 256, 0, stream>>>(Whh0, Whh1, Wih1, Wih0,
                                     whh0_fr, whh1_fr, wih1_bf, wih0_bf);
  gemm_pre<256, true><<<2048, 256, 0, stream>>>(embed, x, nullptr, wih0_bf, bih0, bhh0, pre);
  recur<true><<<128, 512, 0, stream>>>(pre, whh0_fr, outs0, nullptr);
  gemm_pre<512, false><<<2048, 256, 0, stream>>>(nullptr, nullptr, outs0, wih1_bf, bih1, bhh1, pre);
  recur<false><<<128, 512, 0, stream>>>(pre, whh1_fr, nullptr, h1);
  predict<<<8, 512, 0, stream>>>(h1, Wpred, bpred, out);
}

// Round 12
// 446.139 us; speedup vs baseline: 2.3315x; 2.3315x over previous
//
#include <hip/hip_runtime.h>
#include <hip/hip_bf16.h>

typedef __attribute__((ext_vector_type(4))) float f32x4;
typedef __attribute__((ext_vector_type(8))) short short8;

#define DEVI __device__ __forceinline__

DEVI unsigned short f2bf(float x) {
  union { float f; unsigned u; } v; v.f = x;
  unsigned r = v.u + 0x7fffu + ((v.u >> 16) & 1u);
  return (unsigned short)(r >> 16);
}
DEVI float bf2f(unsigned short h) {
  union { unsigned u; float f; } v; v.u = ((unsigned)h) << 16;
  return v.f;
}

DEVI void gld16(const void* g, void* l) {
  __builtin_amdgcn_global_load_lds(
      (const __attribute__((address_space(1))) void*)g,
      (__attribute__((address_space(3))) void*)l, 16, 0, 0);
}

// ---------- prep ----------
// whh0/whh1 -> bf16 in MFMA-fragment order (kt-major; r8 layout):
//   element e: slot=e>>3, r=e&7; lane=slot&63, ni=(slot>>6)&3, wd=(slot>>8)&7,
//   kt=slot>>11; col=wd*64+ni*16+(lane&15); kr=kt*32+(lane>>4)*8+r.
// wih0/wih1 -> plain bf16; embed -> plain bf16 (for gld16 gather staging).
__global__ __launch_bounds__(256) void prep_cvt(
    const float* __restrict__ whh0, const float* __restrict__ whh1,
    const float* __restrict__ wih1, const float* __restrict__ wih0,
    const float* __restrict__ embed,
    short* __restrict__ o_whh0fr, short* __restrict__ o_whh1fr,
    short* __restrict__ o_wih1, short* __restrict__ o_wih0,
    short* __restrict__ o_emb) {
  int i = blockIdx.x * 256 + threadIdx.x;
  if (i < 524288) {
    const float* src = (i < 262144) ? whh0 : whh1;
    short* dst = (i < 262144) ? o_whh0fr : o_whh1fr;
    int e = i & 262143;
    int slot = e >> 3, r = e & 7;
    int lane = slot & 63, ni = (slot >> 6) & 3, wd = (slot >> 8) & 7, kt = slot >> 11;
    int col = wd * 64 + ni * 16 + (lane & 15);
    int kr = kt * 32 + (lane >> 4) * 8 + r;
    dst[e] = (short)f2bf(src[col * 512 + kr]);
    return;
  }
  if (i < 786432) { int j = i - 524288; o_wih1[j] = (short)f2bf(wih1[j]); return; }
  if (i < 917504) { int j = i - 786432; o_wih0[j] = (short)f2bf(wih0[j]); return; }
  {
    int j = i - 917504;
    if (j < 8192000) o_emb[j] = (short)f2bf(embed[j]);
  }
}

// ---------- GEMM: pre = A @ W^T + bias_a + bias_b  (bf16 out) ----------
// m97-style: 128x128 tile, BK=64, double-buffered LDS, gld16 staging with
// pre-swizzled per-lane sources (fixed across the K loop), 1 barrier/iter.
// 256 threads = 4 waves (2x2 of 64x64).
template<int KDIM, bool GATHER>
__global__ __launch_bounds__(256) void gemm_pre(
    const short* __restrict__ embbf, const int* __restrict__ xtok,
    const short* __restrict__ Abf, const short* __restrict__ Bbf,
    const float* __restrict__ bias_a, const float* __restrict__ bias_b,
    short* __restrict__ out) {
  __shared__ __align__(16) char smem[65536];  // buf b: A @ b*32768, B @ b*32768+16384
  const int tid = threadIdx.x;
  const int bM = (int)blockIdx.x >> 2;
  const int bN = (int)blockIdx.x & 3;
  const int m0 = bM * 128, n0 = bN * 128;
  const int lane = tid & 63, wid = tid >> 6;
  const int wm = wid >> 1, wn = wid & 1;
  const int l15 = lane & 15, lk = lane >> 4;

  // per-lane staging sources: instr i covers tile rows wid*32+i*8 .. +8,
  // lane -> row wid*32+i*8+(lane>>3), source chunk (lane&7)^(row&7) (XOR swz).
  const char* aSrc[4];
  const char* bSrc[4];
#pragma unroll
  for (int i = 0; i < 4; ++i) {
    int rloc = wid * 32 + i * 8 + (lane >> 3);
    int chunk = (((lane & 7) ^ (rloc & 7)) << 4);
    if (GATHER) {
      int r = m0 + rloc;
      int t = r >> 11, n = r & 2047;
      int tok = xtok[(n << 5) + t];
      aSrc[i] = (const char*)(embbf + (size_t)tok * 256) + chunk;
    } else {
      aSrc[i] = (const char*)(Abf + (size_t)(m0 + rloc) * KDIM) + chunk;
    }
    bSrc[i] = (const char*)(Bbf + (size_t)(n0 + rloc) * KDIM) + chunk;
  }

  f32x4 acc[4][4];
#pragma unroll
  for (int i = 0; i < 4; ++i)
#pragma unroll
    for (int j = 0; j < 4; ++j) acc[i][j] = (f32x4){0.f, 0.f, 0.f, 0.f};

#define STAGE(BUF, KB)                                        \
  do {                                                        \
    char* ab = smem + (BUF)*32768 + wid * 4096;               \
    char* bb = smem + (BUF)*32768 + 16384 + wid * 4096;       \
    _Pragma("unroll") for (int i = 0; i < 4; ++i) {           \
      gld16(aSrc[i] + (size_t)(KB)*2, ab + i * 1024);         \
      gld16(bSrc[i] + (size_t)(KB)*2, bb + i * 1024);         \
    }                                                         \
  } while (0)

  STAGE(0, 0);
  int cur = 0;
  for (int kb = 0; kb < KDIM; kb += 64) {
    __syncthreads();  // staged buf[cur] ready (barrier drains vmcnt); prev reads done
    if (kb + 64 < KDIM) STAGE(cur ^ 1, kb + 64);
    const char* As = smem + cur * 32768;
    const char* Bs = As + 16384;
#pragma unroll
    for (int kt = 0; kt < 2; ++kt) {
      short8 av[4], bv[4];
#pragma unroll
      for (int mi = 0; mi < 4; ++mi) {
        int row = wm * 64 + mi * 16 + l15;
        int off = (row * 128 + kt * 64 + lk * 16) ^ ((row & 7) << 4);
        av[mi] = *(const short8*)(As + off);
      }
#pragma unroll
      for (int ni = 0; ni < 4; ++ni) {
        int col = wn * 64 + ni * 16 + l15;
        int off = (col * 128 + kt * 64 + lk * 16) ^ ((col & 7) << 4);
        bv[ni] = *(const short8*)(Bs + off);
      }
#pragma unroll
      for (int mi = 0; mi < 4; ++mi)
#pragma unroll
        for (int ni = 0; ni < 4; ++ni)
          acc[mi][ni] = __builtin_amdgcn_mfma_f32_16x16x32_bf16(av[mi], bv[ni], acc[mi][ni], 0, 0, 0);
    }
    cur ^= 1;
  }
#undef STAGE

  __syncthreads();  // all waves done with As/Bs before Cs reuse
  float bsum[4];
#pragma unroll
  for (int ni = 0; ni < 4; ++ni) {
    int cg = n0 + wn * 64 + ni * 16 + l15;
    bsum[ni] = bias_a[cg] + bias_b[cg];
  }
  short* Cs = (short*)smem;
#pragma unroll
  for (int mi = 0; mi < 4; ++mi)
#pragma unroll
    for (int ni = 0; ni < 4; ++ni)
#pragma unroll
      for (int r = 0; r < 4; ++r) {
        int row = wm * 64 + mi * 16 + lk * 4 + r;
        int col = wn * 64 + ni * 16 + l15;
        Cs[row * 128 + col] = (short)f2bf(acc[mi][ni][r] + bsum[ni]);
      }
  __syncthreads();
  {
    int row = tid >> 1, colh = (tid & 1) * 64;
    size_t gbase = (size_t)(m0 + row) * 512 + n0 + colh;
#pragma unroll
    for (int c = 0; c < 8; ++c)
      *(short8*)(out + gbase + c * 8) = *(const short8*)&Cs[row * 128 + colh + c * 8];
  }
}

// ---------- recurrence (r8, verbatim): h_t = relu(pre_t + h_{t-1} @ W^T) ----------
template<bool WRITE_OUTS>
__global__ __launch_bounds__(512) void recur(
    const short* __restrict__ pre,   // [32][2048][512] bf16
    const short* __restrict__ wfr,   // W_hh in fragment order (see prep)
    short* __restrict__ outs,        // [32][2048][512] bf16 (WRITE_OUTS)
    float* __restrict__ hlast) {     // [2048][512] f32 (!WRITE_OUTS)
  __shared__ __align__(16) char lds[163840];
  char* Wst  = lds;            // 64 KB: [wid][kt0..1][ni][lane]16B
  char* ring = lds + 65536;    // 64 KB: [wid][slot0..1][ni][lane]16B
  char* hl   = lds + 131072;   // 16 KB: h tile 16x512 bf16, XOR-swizzled
  char* plds = lds + 147456;   // 16 KB: pre tile 16x512 bf16, linear
  const int tid = threadIdx.x;
  const int lane = tid & 63, wid = tid >> 6;
  const int l15 = lane & 15, lk = lane >> 4;
  const int n0 = (int)blockIdx.x * 16;

  const short* wsl = wfr + wid * 2048 + lane * 8;  // per-lane frag source base
  char* wstw = Wst + wid * 8192;
  char* ringw = ring + wid * 8192;

  // prologue: stationary kt0,kt1 (8 gld16) then ring kt2->S0, kt3->S1 (8)
#pragma unroll
  for (int kt = 0; kt < 2; ++kt)
#pragma unroll
    for (int ni = 0; ni < 4; ++ni)
      gld16(wsl + kt * 16384 + ni * 512, wstw + (kt * 4 + ni) * 1024);
#pragma unroll
  for (int s = 0; s < 2; ++s)
#pragma unroll
    for (int ni = 0; ni < 4; ++ni)
      gld16(wsl + (2 + s) * 16384 + ni * 512, ringw + s * 4096 + ni * 1024);

  {  // zero h(-1)
    short8 z = {0, 0, 0, 0, 0, 0, 0, 0};
    *(short8*)(hl + tid * 32) = z;
    *(short8*)(hl + tid * 32 + 16) = z;
  }
  __syncthreads();

  const int axor = (l15 & 7) << 4;
  const char* abase = hl + l15 * 1024;
  const int crow = tid >> 5, cseg = tid & 31;
  const int cxor = (crow & 7) << 4;

#pragma unroll 1
  for (int t = 0; t < 32; ++t) {
    // P: stage pre rows 2*wid, 2*wid+1 (consumed after B1)
    {
      const short* psrc = pre + ((size_t)t * 2048 + n0) * 512;
      gld16(psrc + wid * 1024 + lane * 8, plds + wid * 2048);
      gld16(psrc + wid * 1024 + 512 + lane * 8, plds + wid * 2048 + 1024);
    }

    f32x4 acc[4];
#pragma unroll
    for (int ni = 0; ni < 4; ++ni) acc[ni] = (f32x4){0.f, 0.f, 0.f, 0.f};

    // stationary kt0,kt1 (wait retires the 8 prologue staging loads at t=0)
    asm volatile("s_waitcnt vmcnt(10)" ::: "memory");
#pragma unroll
    for (int kt = 0; kt < 2; ++kt) {
      short8 a = *(const short8*)(abase + ((kt * 64 + lk * 16) ^ axor));
#pragma unroll
      for (int ni = 0; ni < 4; ++ni) {
        short8 b = *(const short8*)(wstw + (kt * 4 + ni) * 1024 + lane * 16);
        acc[ni] = __builtin_amdgcn_mfma_f32_16x16x32_bf16(a, b, acc[ni], 0, 0, 0);
      }
    }

    // streamed kt2..15 through the 2-slot ring
#pragma unroll
    for (int j = 0; j < 14; ++j) {
      const int kt = 2 + j;
      char* slot = ringw + (j & 1) * 4096;
      if (j < 2) { asm volatile("s_waitcnt vmcnt(6)" ::: "memory"); }
      else       { asm volatile("s_waitcnt vmcnt(4)" ::: "memory"); }
      short8 a  = *(const short8*)(abase + ((kt * 64 + lk * 16) ^ axor));
      short8 b0 = *(const short8*)(slot + lane * 16);
      short8 b1 = *(const short8*)(slot + 1024 + lane * 16);
      short8 b2 = *(const short8*)(slot + 2048 + lane * 16);
      short8 b3 = *(const short8*)(slot + 3072 + lane * 16);
      acc[0] = __builtin_amdgcn_mfma_f32_16x16x32_bf16(a, b0, acc[0], 0, 0, 0);
      acc[1] = __builtin_amdgcn_mfma_f32_16x16x32_bf16(a, b1, acc[1], 0, 0, 0);
      acc[2] = __builtin_amdgcn_mfma_f32_16x16x32_bf16(a, b2, acc[2], 0, 0, 0);
      acc[3] = __builtin_amdgcn_mfma_f32_16x16x32_bf16(a, b3, acc[3], 0, 0, 0);
      // refill this slot: kt+2 (j<12) or next step's kt2/kt3 (j>=12)
      const int ktr = (j < 12) ? (kt + 2) : (kt - 12);
      const short* rs = wsl + ktr * 16384;
#pragma unroll
      for (int ni = 0; ni < 4; ++ni)
        gld16(rs + ni * 512, slot + ni * 1024);
    }

    // stream h(t-1) to outs (reads hl; must precede B1/epilogue)
    if (WRITE_OUTS && t > 0) {
      short8 v0 = *(const short8*)(hl + crow * 1024 + ((cseg * 32) ^ cxor));
      short8 v1 = *(const short8*)(hl + crow * 1024 + ((cseg * 32 + 16) ^ cxor));
      short* dst = outs + ((size_t)(t - 1) * 2048 + n0 + crow) * 512 + cseg * 16;
      *(short8*)dst = v0;
      *(short8*)(dst + 8) = v1;
    }

    __syncthreads();  // B1: drains vmcnt(0) -> plds/ring staged; h reads done

    // epilogue: h(t) = relu(acc + pre) in place (XOR-swizzled)
#pragma unroll
    for (int r = 0; r < 4; ++r) {
      int row = lk * 4 + r;
      int rxor = (row & 7) << 4;
#pragma unroll
      for (int ni = 0; ni < 4; ++ni) {
        int col = wid * 64 + ni * 16 + l15;
        float pvf = bf2f(*(const unsigned short*)(plds + row * 1024 + col * 2));
        float v = fmaxf(acc[ni][r] + pvf, 0.f);
        *(short*)(hl + row * 1024 + ((col * 2) ^ rxor)) = (short)f2bf(v);
        if (!WRITE_OUTS && t == 31) hlast[(size_t)(n0 + row) * 512 + col] = v;
      }
    }
    __syncthreads();  // B2: h(t) visible to all
  }

  if (WRITE_OUTS) {
    short8 v0 = *(const short8*)(hl + crow * 1024 + ((cseg * 32) ^ cxor));
    short8 v1 = *(const short8*)(hl + crow * 1024 + ((cseg * 32 + 16) ^ cxor));
    short* dst = outs + ((size_t)31 * 2048 + n0 + crow) * 512 + cseg * 16;
    *(short8*)dst = v0;
    *(short8*)(dst + 8) = v1;
  }
}

// ---------- head: s[b,n] = h_n.(wl-wg) + (sum_n h).wg + b_pred ----------
__global__ __launch_bounds__(512) void predict(
    const float* __restrict__ h1, const float* __restrict__ Wp,
    const float* __restrict__ bp, float* __restrict__ out) {
  const int b = blockIdx.x, tid = threadIdx.x;
  const int lane = tid & 63, wid = tid >> 6;
  __shared__ float red[8];
  __shared__ float sgd_s;
  const float* hb = h1 + (size_t)b * 256 * 512;
  float s = 0.f;
  for (int n = 0; n < 256; ++n) s += hb[(size_t)n * 512 + tid];
  float p = s * Wp[512 + tid];
#pragma unroll
  for (int o = 32; o; o >>= 1) p += __shfl_xor(p, o);
  if (lane == 0) red[wid] = p;
  __syncthreads();
  if (tid == 0) {
    float q = 0.f;
#pragma unroll
    for (int i = 0; i < 8; ++i) q += red[i];
    sgd_s = q;
  }
  __syncthreads();
  const float sgd = sgd_s + bp[0];
  float wd[8];
  const int k0 = lane * 8;
#pragma unroll
  for (int j = 0; j < 8; ++j) wd[j] = Wp[k0 + j] - Wp[512 + k0 + j];
  for (int c = 0; c < 32; ++c) {
    int n = wid * 32 + c;
    const float* hr = hb + (size_t)n * 512 + k0;
    float d = 0.f;
#pragma unroll
    for (int j = 0; j < 8; ++j) d += hr[j] * wd[j];
#pragma unroll
    for (int o = 1; o < 64; o <<= 1) d += __shfl_xor(d, o);
    if (lane == 0) out[b * 256 + n] = d + sgd;
  }
}

extern "C" void kernel_launch(void* const* d_in, const int* in_sizes, int n_in,
                              void* d_out, int out_size, void* d_ws, size_t ws_size,
                              hipStream_t stream) {
  const int* x = (const int*)d_in[0];
  const float* embed = (const float*)d_in[1];
  const float* Wih0 = (const float*)d_in[2];
  const float* Whh0 = (const float*)d_in[3];
  const float* bih0 = (const float*)d_in[4];
  const float* bhh0 = (const float*)d_in[5];
  const float* Wih1 = (const float*)d_in[6];
  const float* Whh1 = (const float*)d_in[7];
  const float* bih1 = (const float*)d_in[8];
  const float* bhh1 = (const float*)d_in[9];
  const float* Wpred = (const float*)d_in[10];
  const float* bpred = (const float*)d_in[11];
  float* out = (float*)d_out;

  char* ws = (char*)d_ws;
  short* whh0_fr = (short*)ws;                          // 512 KB (frag order)
  short* whh1_fr = (short*)(ws + 524288);               // 512 KB (frag order)
  short* wih0_bf = (short*)(ws + 1048576);              // 256 KB
  short* wih1_bf = (short*)(ws + 1310720);              // 512 KB
  short* pre     = (short*)(ws + 2097152);              // 64 MB (pre0, then pre1)
  short* outs0   = (short*)(ws + 2097152 + 67108864);   // 64 MB
  float* h1      = (float*)(ws + 2097152 + 2ll * 67108864);  // 4 MB
  // embed_bf aliases outs0: live only during gemm0; outs0 written later by recur0.
  short* emb_bf  = outs0;                               // 16 MB (within outs0's 64)

  prep_cvt<<<35584, 256, 0, stream>>>(Whh0, Whh1, Wih1, Wih0, embed,
                                      whh0_fr, whh1_fr, wih1_bf, wih0_bf, emb_bf);
  gemm_pre<256, true><<<2048, 256, 0, stream>>>(emb_bf, x, nullptr, wih0_bf, bih0, bhh0, pre);
  recur<true><<<128, 512, 0, stream>>>(pre, whh0_fr, outs0, nullptr);
  gemm_pre<512, false><<<2048, 256, 0, stream>>>(nullptr, nullptr, outs0, wih1_bf, bih1, bhh1, pre);
  recur<false><<<128, 512, 0, stream>>>(pre, whh1_fr, nullptr, h1);
  predict<<<8, 512, 0, stream>>>(h1, Wpred, bpred, out);
}